// Round 6
// baseline (218.504 us; speedup 1.0000x reference)
//
#include <hip/hip_runtime.h>
#include <hip/hip_fp16.h>

// ImplicitPointHead fused (MI355X / gfx950) — round 6
// vs r5 (217us, MfmaUtil 31%, VGPR 52 -> pipeline collapsed by compiler):
// WAR-slot register queues that CANNOT be coalesced away:
//   B: 5-slot queue (40 VGPR), consume b[ks%5] then reload same slot with ks+5
//      -> ~4 iterations of guaranteed L2-latency cover, loads pinned by WAR/RAW.
//   A: 2-slot queue (32 VGPR), consume a[ks%2] then reload with ks+2
//      -> ~2 iterations of LDS-latency cover.
// Budget: 32 acc + 40 B + 32 A + misc ~ 124 VGPR <= 128 cliff (16 waves/CU).

#define NI      128
#define NPTS    2048
#define CH      256
#define NPARAM  263169
#define PT      64
#define NTILES  (NPTS / PT)     // 32
#define ROWS    536             // 67x16B per row (odd -> minimal b128 aliasing)

#define WOFF0   0
#define WOFF1   131072
#define WOFF2   196608
#define WOFF3   262144
#define BOFF0   262400
#define BOFF1   262656
#define BOFF2   262912
#define BOFF3   263168

// fragment-layout f16 weight cache in d_ws (per instance, f16 offsets)
#define PI_L0   0        // 16 ks * 16 cb * 64 lane * 8
#define PI_L1   131072
#define PI_L2   196608
#define PI_L3   262144
#define WS_PER_INST 262400
#define WS_BYTES ((size_t)NI * WS_PER_INST * 2)

typedef __fp16   h16x2 __attribute__((ext_vector_type(2)));
typedef _Float16 f16x8 __attribute__((ext_vector_type(8)));
typedef float    f32x4 __attribute__((ext_vector_type(4)));

union pack8 { h16x2 h[4]; f16x8 v; };

// ---------------- prep: params fp32 -> fragment-ordered fp16 ----------------
// Frag cb, lane l covers ch co = (cb>>1)*32 + 2*(l&15) + (cb&1); k = ks*32+(l>>4)*8.
__global__ __launch_bounds__(256) void iph_prep(
    const float* __restrict__ params, _Float16* __restrict__ wsw)
{
    const int inst = blockIdx.y;
    const int r = blockIdx.x * 256 + threadIdx.x;
    if (r >= 32800) return;
    const float* __restrict__ P = params + (size_t)inst * NPARAM;
    _Float16* __restrict__ W = wsw + (size_t)inst * WS_PER_INST;

    int rl, woff, K, dst;
    if (r < 16384)      { rl = r;         woff = WOFF0; K = 512; dst = PI_L0; }
    else if (r < 24576) { rl = r - 16384; woff = WOFF1; K = 256; dst = PI_L1; }
    else if (r < 32768) { rl = r - 24576; woff = WOFF2; K = 256; dst = PI_L2; }
    else {
        const int e = (r - 32768) * 8;
        f16x8 v;
        #pragma unroll
        for (int j = 0; j < 8; ++j) v[j] = (_Float16)P[WOFF3 + e + j];
        *(f16x8*)&W[PI_L3 + e] = v;
        return;
    }
    const int e    = rl * 8;
    const int lane = rl & 63;
    const int cb   = (rl >> 6) & 15;
    const int ks   = rl >> 10;
    const int co   = (cb >> 1) * 32 + 2 * (lane & 15) + (cb & 1);
    const int k    = ks * 32 + (lane >> 4) * 8;
    const float* __restrict__ src = P + woff + co * K + k;
    f16x8 v;
    #pragma unroll
    for (int j = 0; j < 8; ++j) v[j] = (_Float16)src[j];
    *(f16x8*)&W[dst + e] = v;
}

// ---------------- pipelined GEMM tile (WAR-slot queues) ----------------
template<int NKS, bool PREPPED>
__device__ __forceinline__ void gemm_tile(
    f32x4 (&acc)[4][2],
    const _Float16* __restrict__ bsrc,   // WI + PI_Lx (fragment order)
    const float* __restrict__ pw,        // P + WOFFx (fallback)
    const _Float16* __restrict__ X,
    int lane, int wave, int l15, int hi)
{
    if constexpr (PREPPED) {
        constexpr int BW = (NKS < 5) ? NKS : 5;   // B queue depth
        const _Float16* bp = bsrc + ((wave * 2) * 64 + lane) * 8;
        const _Float16* ap = &X[l15 * ROWS + hi * 8];

        f16x8 b[BW][2];
        f16x8 a[2][4];
        #pragma unroll
        for (int i = 0; i < BW; ++i) {
            b[i][0] = *(const f16x8*)(bp + i * 8192);
            b[i][1] = *(const f16x8*)(bp + i * 8192 + 512);
        }
        #pragma unroll
        for (int mt = 0; mt < 4; ++mt) {
            a[0][mt] = *(const f16x8*)(ap + mt * 16 * ROWS);
            if (NKS > 1) a[1][mt] = *(const f16x8*)(ap + mt * 16 * ROWS + 32);
        }

        #pragma unroll
        for (int ks = 0; ks < NKS; ++ks) {          // fully unrolled: all idx static
            const int as = ks & 1;
            const int bs = ks % BW;
            __builtin_amdgcn_s_setprio(1);
            #pragma unroll
            for (int mt = 0; mt < 4; ++mt) {
                acc[mt][0] = __builtin_amdgcn_mfma_f32_16x16x32_f16(a[as][mt], b[bs][0], acc[mt][0], 0, 0, 0);
                acc[mt][1] = __builtin_amdgcn_mfma_f32_16x16x32_f16(a[as][mt], b[bs][1], acc[mt][1], 0, 0, 0);
            }
            __builtin_amdgcn_s_setprio(0);
            // refill the just-consumed slots (WAR-pinned: can't move above the
            // MFMAs; RAW at ks+BW / ks+2 pins the lower bound)
            if (ks + BW < NKS) {
                b[bs][0] = *(const f16x8*)(bp + (ks + BW) * 8192);
                b[bs][1] = *(const f16x8*)(bp + (ks + BW) * 8192 + 512);
            }
            if (ks + 2 < NKS) {
                #pragma unroll
                for (int mt = 0; mt < 4; ++mt)
                    a[as][mt] = *(const f16x8*)(ap + mt * 16 * ROWS + (ks + 2) * 32);
            }
        }
    } else {
        const int K = NKS * 32;
        for (int ks = 0; ks < NKS; ++ks) {
            f16x8 bfrag[2];
            #pragma unroll
            for (int nt = 0; nt < 2; ++nt) {
                const int co = wave * 32 + 2 * l15 + nt;
                const float* wp = pw + (size_t)co * K + ks * 32 + hi * 8;
                float w8[8];
                __builtin_memcpy(w8, wp, 32);
                f16x8 bb;
                #pragma unroll
                for (int j = 0; j < 8; ++j) bb[j] = (_Float16)w8[j];
                bfrag[nt] = bb;
            }
            f16x8 afrag[4];
            #pragma unroll
            for (int mt = 0; mt < 4; ++mt)
                afrag[mt] = *(const f16x8*)&X[(mt * 16 + l15) * ROWS + ks * 32 + hi * 8];
            #pragma unroll
            for (int mt = 0; mt < 4; ++mt)
                #pragma unroll
                for (int nt = 0; nt < 2; ++nt)
                    acc[mt][nt] = __builtin_amdgcn_mfma_f32_16x16x32_f16(
                        afrag[mt], bfrag[nt], acc[mt][nt], 0, 0, 0);
        }
    }
}

// ---------------- main fused kernel ----------------
template<bool PREPPED>
__global__ __launch_bounds__(512, 4) void iph_main(
    const float* __restrict__ feat,     // [128][256][2048]
    const float* __restrict__ coords,   // [128][2048][2]
    const float* __restrict__ params,   // [128][263169]
    const _Float16* __restrict__ wsw,   // fragment-ordered f16 weights
    const float* __restrict__ peg,      // [2][128]
    float* __restrict__ out)            // [128][1][2048]
{
    __shared__ _Float16 X[PT * ROWS];   // 68608 B
    __shared__ float    partial[8][PT]; // 2 KB -> total 70.7 KB, 2 blocks/CU

    const int bid  = blockIdx.x;
    const int inst = (bid & 7) | ((bid >> 8) << 3);
    const int tile = (bid >> 3) & 31;
    const int p0   = tile * PT;
    const int tid  = threadIdx.x;
    const int lane = tid & 63;
    const int wave = tid >> 6;
    const int l15  = lane & 15;
    const int hi   = lane >> 4;
    const float* __restrict__ P = params + (size_t)inst * NPARAM;
    const _Float16* __restrict__ WI = wsw + (size_t)inst * WS_PER_INST;

    // ---- positional encoding -> X[pt][0..255], b128 writes
    {
        const int pt   = tid >> 3;     // 64 pts
        const int part = tid & 7;      // 16 freqs each
        const float2 cc = *(const float2*)&coords[((size_t)inst * NPTS + p0 + pt) * 2];
        const float a = 2.f * cc.x - 1.f;
        const float b = 2.f * cc.y - 1.f;
        float sv[16], cv[16];
        #pragma unroll
        for (int j = 0; j < 16; ++j) {
            const int f = part * 16 + j;
            float locr = a * peg[f] + b * peg[128 + f];
            locr -= floorf(locr);                        // period-1 reduction
            sv[j] = __builtin_amdgcn_sinf(locr);         // sin(2*pi*x)
            cv[j] = __builtin_amdgcn_cosf(locr);
        }
        pack8 s0, s1, c0, c1;
        #pragma unroll
        for (int q = 0; q < 4; ++q) {
            s0.h[q] = __builtin_amdgcn_cvt_pkrtz(sv[2*q],     sv[2*q + 1]);
            s1.h[q] = __builtin_amdgcn_cvt_pkrtz(sv[8 + 2*q], sv[9 + 2*q]);
            c0.h[q] = __builtin_amdgcn_cvt_pkrtz(cv[2*q],     cv[2*q + 1]);
            c1.h[q] = __builtin_amdgcn_cvt_pkrtz(cv[8 + 2*q], cv[9 + 2*q]);
        }
        _Float16* base = &X[pt * ROWS + part * 16];
        *(f16x8*)(base)           = s0.v;
        *(f16x8*)(base + 8)       = s1.v;
        *(f16x8*)(base + 128)     = c0.v;
        *(f16x8*)(base + 136)     = c1.v;
    }
    // ---- features -> X[pt][256..511], 8 dword loads -> one b128 write
    {
        const float* fbase = feat + (size_t)inst * CH * NPTS + p0 + lane;
        #pragma unroll
        for (int s = 0; s < 4; ++s) {
            const int c0i = s * 64 + wave * 8;
            float w8[8];
            #pragma unroll
            for (int j = 0; j < 8; ++j)
                w8[j] = fbase[(size_t)(c0i + j) * NPTS];
            pack8 pk;
            #pragma unroll
            for (int q = 0; q < 4; ++q)
                pk.h[q] = __builtin_amdgcn_cvt_pkrtz(w8[2*q], w8[2*q + 1]);
            *(f16x8*)&X[lane * ROWS + 256 + c0i] = pk.v;
        }
    }
    __syncthreads();

    // hidden-layer epilogue: relu(acc+b) -> X (even/odd half2 writes)
    auto write_epilogue = [&](f32x4 (&acc)[4][2], const float2 bb) {
        #pragma unroll
        for (int mt = 0; mt < 4; ++mt) {
            #pragma unroll
            for (int r = 0; r < 4; ++r) {
                // C/D layout (m89): col=lane&15, row=(lane>>4)*4+r
                const float v0 = fmaxf(acc[mt][0][r] + bb.x, 0.f);
                const float v1 = fmaxf(acc[mt][1][r] + bb.y, 0.f);
                const h16x2 e = __builtin_amdgcn_cvt_pkrtz(v0, v1);
                const int pt = mt * 16 + hi * 4 + r;
                *(h16x2*)&X[pt * ROWS + wave * 32 + 2 * l15] = e;
            }
        }
    };

    // ---- L0
    {
        f32x4 acc[4][2];
        #pragma unroll
        for (int mt = 0; mt < 4; ++mt)
            #pragma unroll
            for (int nt = 0; nt < 2; ++nt)
                acc[mt][nt] = (f32x4){0.f, 0.f, 0.f, 0.f};
        const float2 bb = *(const float2*)&P[BOFF0 + wave * 32 + 2 * l15];
        gemm_tile<16, PREPPED>(acc, WI + PI_L0, P + WOFF0, X, lane, wave, l15, hi);
        __syncthreads();
        write_epilogue(acc, bb);
        __syncthreads();
    }
    // ---- L1
    {
        f32x4 acc[4][2];
        #pragma unroll
        for (int mt = 0; mt < 4; ++mt)
            #pragma unroll
            for (int nt = 0; nt < 2; ++nt)
                acc[mt][nt] = (f32x4){0.f, 0.f, 0.f, 0.f};
        const float2 bb = *(const float2*)&P[BOFF1 + wave * 32 + 2 * l15];
        gemm_tile<8, PREPPED>(acc, WI + PI_L1, P + WOFF1, X, lane, wave, l15, hi);
        __syncthreads();
        write_epilogue(acc, bb);
        __syncthreads();
    }
    // ---- L2 + L3 fused: partial[wave][pt] = sum_{ch in wave} w3[ch]*relu(acc+b2)
    {
        f32x4 acc[4][2];
        #pragma unroll
        for (int mt = 0; mt < 4; ++mt)
            #pragma unroll
            for (int nt = 0; nt < 2; ++nt)
                acc[mt][nt] = (f32x4){0.f, 0.f, 0.f, 0.f};
        const float2 bb = *(const float2*)&P[BOFF2 + wave * 32 + 2 * l15];
        const float2 w3 = *(const float2*)&P[WOFF3 + wave * 32 + 2 * l15];
        gemm_tile<8, PREPPED>(acc, WI + PI_L2, P + WOFF2, X, lane, wave, l15, hi);
        #pragma unroll
        for (int mt = 0; mt < 4; ++mt) {
            #pragma unroll
            for (int r = 0; r < 4; ++r) {
                const float v0 = fmaxf(acc[mt][0][r] + bb.x, 0.f);
                const float v1 = fmaxf(acc[mt][1][r] + bb.y, 0.f);
                float s = v0 * w3.x + v1 * w3.y;
                s += __shfl_xor(s, 1);
                s += __shfl_xor(s, 2);
                s += __shfl_xor(s, 4);
                s += __shfl_xor(s, 8);
                if (l15 == 0)
                    partial[wave][mt * 16 + hi * 4 + r] = s;
            }
        }
        __syncthreads();
        if (tid < PT) {
            float s = P[BOFF3];
            #pragma unroll
            for (int w = 0; w < 8; ++w) s += partial[w][tid];
            out[(size_t)inst * NPTS + p0 + tid] = s;
        }
    }
}

extern "C" void kernel_launch(void* const* d_in, const int* in_sizes, int n_in,
                              void* d_out, int out_size, void* d_ws, size_t ws_size,
                              hipStream_t stream) {
    (void)in_sizes; (void)n_in; (void)out_size;
    const float* feat   = (const float*)d_in[0];
    const float* coords = (const float*)d_in[1];
    const float* params = (const float*)d_in[2];
    const float* peg    = (const float*)d_in[3];
    float* out = (float*)d_out;

    dim3 grid(NI * NTILES);   // 4096 blocks
    dim3 block(512);

    if (ws_size >= WS_BYTES) {
        _Float16* wsw = (_Float16*)d_ws;
        iph_prep<<<dim3(129, 128), dim3(256), 0, stream>>>(params, wsw);
        iph_main<true><<<grid, block, 0, stream>>>(feat, coords, params, wsw, peg, out);
    } else {
        iph_main<false><<<grid, block, 0, stream>>>(feat, coords, params,
                                                    (const _Float16*)d_ws, peg, out);
    }
}